// Round 8
// baseline (377.925 us; speedup 1.0000x reference)
//
#include <hip/hip_runtime.h>
#include <hip/hip_bf16.h>
#include <hip/hip_cooperative_groups.h>

namespace cg = cooperative_groups;

#define BB 4
#define SS 32
#define HH 8
#define LL 128
#define DD 512
#define DI 2048
#define EPSN 1e-6f
#define INV_TEMP 0.04419417382415922f   // 1/sqrt(512)

#define NCAST_GRAN ((DI*DD/4)*2 + (DD*DD/4))   // 589824 float4 granules
#define NROW (BB*SS*HH)                  // 1024 rows
#define SLICE ((size_t)NROW * DD)        // floats per K-split partial

#define GRID 256
#define BLK  512

#define NLOGIT_BLK 4096                  // fallback pre_kernel
#define NCAST_BLK (NCAST_GRAN / 256)     // 2304

typedef __attribute__((ext_vector_type(8))) short short8;
typedef __attribute__((ext_vector_type(4))) float float4v;

static __device__ __forceinline__ unsigned short f2b(float f) {
  __hip_bfloat16 h = __float2bfloat16(f);
  return *(unsigned short*)&h;
}

struct MegaParams {
  const float* x; const int* mask; const float* w; const float* v_w;
  const float* ln_g; const float* ln_b;
  const float* w1; const float* b1; const float* w2; const float* b2;
  const float* fln_g; const float* fln_b;
  float* y; float* attn;
  unsigned short* w1b; unsigned short* w2b; unsigned short* v_wb;
  unsigned short* o_lnb; unsigned short* h1b; unsigned short* xab;
  float* logits; float* o_ln; float* vpart; float* ypart;
};

// ===========================================================================
// Cooperative mega-kernel: 256 blocks x 512 threads (1 block/CU — always
// co-resident).  Stages separated by grid.sync().
// ===========================================================================
__global__ __launch_bounds__(BLK, 2) void mega_kernel(MegaParams p) {
  cg::grid_group grid = cg::this_grid();
  int blk = blockIdx.x;
  int t = threadIdx.x, wv = t >> 6, lane = t & 63;
  int lm = lane & 15, lq = lane >> 4;

  __shared__ float sattn_t[LL][HH];      // 4 KB   (S2)
  __shared__ float sxa[2][HH][256];      // 16 KB  (S2)

  // ---------------- S1a: cast w1,w2,v_w to bf16 ----------------
  {
    const int n1 = (DI * DD) / 4;
    const int n2 = n1;
    for (int i = blk * BLK + t; i < NCAST_GRAN; i += GRID * BLK) {
      const float4* src;
      unsigned short* dst;
      int j = i;
      if (i < n1)           { src = (const float4*)p.w1;  dst = p.w1b; }
      else if (i < n1 + n2) { src = (const float4*)p.w2;  dst = p.w2b;  j = i - n1; }
      else                  { src = (const float4*)p.v_w; dst = p.v_wb; j = i - n1 - n2; }
      float4 v = src[j];
      dst[j * 4 + 0] = f2b(v.x);
      dst[j * 4 + 1] = f2b(v.y);
      dst[j * 4 + 2] = f2b(v.z);
      dst[j * 4 + 3] = f2b(v.w);
    }
  }
  // ---------------- S1b: logits, 8 (bs,l) tasks per wave ----------------
  {
    int gw = blk * 8 + wv;               // 2048 waves
#pragma unroll
    for (int i = 0; i < 8; ++i) {
      int pp = gw * 8 + i;               // 16384 tasks
      int bs = pp >> 7, l = pp & (LL - 1);
      const float4* xr = (const float4*)(p.x + ((size_t)bs * LL + l) * DD) + lane * 2;
      float4 x0 = xr[0], x1 = xr[1];
      float acc[HH];
#pragma unroll
      for (int h = 0; h < HH; ++h) {
        const float4* wr = (const float4*)(p.w + ((size_t)h * LL + l) * DD) + lane * 2;
        float4 w0 = wr[0], w1v = wr[1];
        acc[h] = x0.x * w0.x + x0.y * w0.y + x0.z * w0.z + x0.w * w0.w +
                 x1.x * w1v.x + x1.y * w1v.y + x1.z * w1v.z + x1.w * w1v.w;
      }
#pragma unroll
      for (int off = 32; off > 0; off >>= 1) {
#pragma unroll
        for (int h = 0; h < HH; ++h) acc[h] += __shfl_xor(acc[h], off);
      }
      if (lane == 0) {
        int msk = p.mask[bs * LL + l];
#pragma unroll
        for (int h = 0; h < HH; ++h) {
          float lg = msk ? acc[h] * INV_TEMP : -1e9f;
          p.logits[((size_t)bs * HH + h) * LL + l] = lg;
        }
      }
    }
  }
  grid.sync();

  // ---------------- S2: softmax + xa (all 256 blocks) ----------------
  {
    int bs = blk >> 1, half = blk & 1;
    if (wv < 4) {
      for (int h = wv; h < HH; h += 4) {
        const float* lg = p.logits + ((size_t)bs * HH + h) * LL;
        float v0 = lg[lane], v1 = lg[lane + 64];
        float m = fmaxf(v0, v1);
#pragma unroll
        for (int off = 32; off > 0; off >>= 1) m = fmaxf(m, __shfl_xor(m, off));
        float e0 = __expf(v0 - m), e1 = __expf(v1 - m);
        float s = e0 + e1;
#pragma unroll
        for (int off = 32; off > 0; off >>= 1) s += __shfl_xor(s, off);
        float inv = 1.f / s;
        e0 *= inv; e1 *= inv;
        sattn_t[lane][h]      = e0;
        sattn_t[lane + 64][h] = e1;
        if (half == 0) {
          float* ao = p.attn + ((size_t)bs * HH + h) * LL;
          ao[lane]      = e0;
          ao[lane + 64] = e1;
        }
      }
    }
    __syncthreads();

    int col = t & 255, lseg = t >> 8;
    int e = half * 256 + col;
    const float* xb = p.x + (size_t)bs * LL * DD;
    float acc[HH];
#pragma unroll
    for (int h = 0; h < HH; ++h) acc[h] = 0.f;
    int l0 = lseg * 64;
    for (int l = l0; l < l0 + 64; ++l) {
      float xv = xb[(size_t)l * DD + e];
      float4 a0 = *(const float4*)&sattn_t[l][0];
      float4 a1 = *(const float4*)&sattn_t[l][4];
      acc[0] += a0.x * xv; acc[1] += a0.y * xv;
      acc[2] += a0.z * xv; acc[3] += a0.w * xv;
      acc[4] += a1.x * xv; acc[5] += a1.y * xv;
      acc[6] += a1.z * xv; acc[7] += a1.w * xv;
    }
#pragma unroll
    for (int h = 0; h < HH; ++h) sxa[lseg][h][col] = acc[h];
    __syncthreads();
    if (t < 256) {
      unsigned short* xo = p.xab + (size_t)bs * HH * DD;
#pragma unroll
      for (int h = 0; h < HH; ++h)
        xo[h * DD + t + half * 256] = f2b(sxa[0][h][t] + sxa[1][h][t]);
    }
  }
  grid.sync();

  // ---------------- S3: gemm_v, 64x64 tiles, 8 waves, K-split x2 ----------------
  {
    int ks = blk >> 7, rem = blk & 127;
    int mt = rem >> 3, nt = rem & 7;
    int m0 = mt * 64 + (wv & 3) * 16;
    int n0 = nt * 64 + (wv >> 2) * 32;
    int g0 = ks * 32;                    // 256-elem K chunk (short8 granules)

    const short8* A0 = (const short8*)(p.xab + (size_t)(m0 + lm) * DD) + g0;
    const short8* Bp[2];
#pragma unroll
    for (int nf = 0; nf < 2; ++nf)
      Bp[nf] = (const short8*)(p.v_wb + (size_t)(n0 + nf * 16 + lm) * DD) + g0;

    float4v acc[2];
#pragma unroll
    for (int nf = 0; nf < 2; ++nf) acc[nf] = (float4v){0.f, 0.f, 0.f, 0.f};
#pragma unroll 4
    for (int ksi = 0; ksi < 8; ++ksi) {
      short8 a0 = A0[ksi * 4 + lq];
      short8 b[2];
#pragma unroll
      for (int nf = 0; nf < 2; ++nf) b[nf] = Bp[nf][ksi * 4 + lq];
#pragma unroll
      for (int nf = 0; nf < 2; ++nf)
        acc[nf] = __builtin_amdgcn_mfma_f32_16x16x32_bf16(a0, b[nf], acc[nf], 0, 0, 0);
    }
    float* outp = p.vpart + (size_t)ks * SLICE;
#pragma unroll
    for (int nf = 0; nf < 2; ++nf) {
      int col = n0 + nf * 16 + lm;
#pragma unroll
      for (int r = 0; r < 4; ++r)
        outp[(size_t)(m0 + lq * 4 + r) * DD + col] = acc[nf][r];
    }
  }
  grid.sync();

  // ---------------- S4: ln_mid (blocks 0-127, wave per row, 2 slices) --------
  if (blk < 128) {
    int row = blk * 8 + wv;
    const float* p0 = p.vpart + (size_t)row * DD;
    float vals[8];
    float sum = 0.f, sq = 0.f;
#pragma unroll
    for (int k = 0; k < 8; ++k) {
      int d = lane + 64 * k;
      float v = p0[d] + p0[SLICE + d];
      vals[k] = v;
      sum += v;
      sq += v * v;
    }
#pragma unroll
    for (int off = 32; off > 0; off >>= 1) {
      sum += __shfl_xor(sum, off);
      sq  += __shfl_xor(sq, off);
    }
    float mu  = sum * (1.f / DD);
    float var = sq * (1.f / DD) - mu * mu;
    float rs  = rsqrtf(var + EPSN);
    float* op = p.o_ln + (size_t)row * DD;
    unsigned short* opb = p.o_lnb + (size_t)row * DD;
#pragma unroll
    for (int k = 0; k < 8; ++k) {
      int d = lane + 64 * k;
      float v = (vals[k] - mu) * rs * p.ln_g[d] + p.ln_b[d];
      op[d]  = v;
      opb[d] = f2b(v);
    }
  }
  grid.sync();

  // ---------------- S5: gemm1, 64x128 tiles, 8 waves, 256 tasks --------------
  {
    int mt = blk >> 4, nt = blk & 15;
    int m0 = mt * 64 + (wv & 3) * 16;
    int n0 = nt * 128 + (wv >> 2) * 64;

    const short8* A0 = (const short8*)(p.o_lnb + (size_t)(m0 + lm) * DD);
    const short8* Bp[4];
#pragma unroll
    for (int nf = 0; nf < 4; ++nf)
      Bp[nf] = (const short8*)(p.w1b + (size_t)(n0 + nf * 16 + lm) * DD);

    float4v acc[4];
#pragma unroll
    for (int nf = 0; nf < 4; ++nf) acc[nf] = (float4v){0.f, 0.f, 0.f, 0.f};
#pragma unroll 4
    for (int ksi = 0; ksi < DD / 32; ++ksi) {
      short8 a0 = A0[ksi * 4 + lq];
      short8 b[4];
#pragma unroll
      for (int nf = 0; nf < 4; ++nf) b[nf] = Bp[nf][ksi * 4 + lq];
#pragma unroll
      for (int nf = 0; nf < 4; ++nf)
        acc[nf] = __builtin_amdgcn_mfma_f32_16x16x32_bf16(a0, b[nf], acc[nf], 0, 0, 0);
    }
#pragma unroll
    for (int nf = 0; nf < 4; ++nf) {
      int col = n0 + nf * 16 + lm;
      float bb = p.b1[col];
#pragma unroll
      for (int r = 0; r < 4; ++r) {
        float v = acc[nf][r] + bb;
        p.h1b[(size_t)(m0 + lq * 4 + r) * DI + col] = f2b(fmaxf(v, 0.f));
      }
    }
  }
  grid.sync();

  // ---------------- S6: gemm2, 64x64 tiles, 8 waves, K-split x2 --------------
  {
    int ks = blk >> 7, rem = blk & 127;
    int mt = rem >> 3, nt = rem & 7;
    int m0 = mt * 64 + (wv & 3) * 16;
    int n0 = nt * 64 + (wv >> 2) * 32;
    int g0 = ks * 128;                   // 1024-elem K chunk (short8 granules)

    const short8* A0 = (const short8*)(p.h1b + (size_t)(m0 + lm) * DI) + g0;
    const short8* Bp[2];
#pragma unroll
    for (int nf = 0; nf < 2; ++nf)
      Bp[nf] = (const short8*)(p.w2b + (size_t)(n0 + nf * 16 + lm) * DI) + g0;

    float4v acc[2];
#pragma unroll
    for (int nf = 0; nf < 2; ++nf) acc[nf] = (float4v){0.f, 0.f, 0.f, 0.f};
#pragma unroll 4
    for (int ksi = 0; ksi < 32; ++ksi) {
      short8 a0 = A0[ksi * 4 + lq];
      short8 b[2];
#pragma unroll
      for (int nf = 0; nf < 2; ++nf) b[nf] = Bp[nf][ksi * 4 + lq];
#pragma unroll
      for (int nf = 0; nf < 2; ++nf)
        acc[nf] = __builtin_amdgcn_mfma_f32_16x16x32_bf16(a0, b[nf], acc[nf], 0, 0, 0);
    }
    float* outp = p.ypart + (size_t)ks * SLICE;
#pragma unroll
    for (int nf = 0; nf < 2; ++nf) {
      int col = n0 + nf * 16 + lm;
#pragma unroll
      for (int r = 0; r < 4; ++r)
        outp[(size_t)(m0 + lq * 4 + r) * DD + col] = acc[nf][r];
    }
  }
  grid.sync();

  // ---------------- S7: ln_final (blocks 0-127, wave per row, 2 slices) ------
  if (blk < 128) {
    int row = blk * 8 + wv;
    const float* p0 = p.ypart + (size_t)row * DD;
    const float* ol = p.o_ln + (size_t)row * DD;
    float vals[8];
    float sum = 0.f, sq = 0.f;
#pragma unroll
    for (int k = 0; k < 8; ++k) {
      int d = lane + 64 * k;
      float v = p0[d] + p0[SLICE + d] + p.b2[d] + ol[d];
      vals[k] = v;
      sum += v;
      sq += v * v;
    }
#pragma unroll
    for (int off = 32; off > 0; off >>= 1) {
      sum += __shfl_xor(sum, off);
      sq  += __shfl_xor(sq, off);
    }
    float mu  = sum * (1.f / DD);
    float var = sq * (1.f / DD) - mu * mu;
    float rs  = rsqrtf(var + EPSN);
    float* yo = p.y + (size_t)row * DD;
#pragma unroll
    for (int k = 0; k < 8; ++k) {
      int d = lane + 64 * k;
      yo[d] = (vals[k] - mu) * rs * p.fln_g[d] + p.fln_b[d];
    }
  }
}

// ===========================================================================
// Fallback path: r5's proven 7-kernel pipeline (172.6 us).
// ===========================================================================
__global__ __launch_bounds__(256) void pre_kernel(
    const float* __restrict__ x, const int* __restrict__ mask,
    const float* __restrict__ w, const float* __restrict__ w1,
    const float* __restrict__ w2, const float* __restrict__ v_w,
    unsigned short* __restrict__ w1b, unsigned short* __restrict__ w2b,
    unsigned short* __restrict__ v_wb, float* __restrict__ logits) {
  int blk = blockIdx.x;
  if (blk < NLOGIT_BLK) {
    int wv = threadIdx.x >> 6, lane = threadIdx.x & 63;
    int p  = blk * 4 + wv;
    int bs = p >> 7, l = p & (LL - 1);

    const float4* xr = (const float4*)(x + ((size_t)bs * LL + l) * DD) + lane * 2;
    float4 x0 = xr[0], x1 = xr[1];

    float acc[HH];
#pragma unroll
    for (int h = 0; h < HH; ++h) {
      const float4* wr = (const float4*)(w + ((size_t)h * LL + l) * DD) + lane * 2;
      float4 w0 = wr[0], w1v = wr[1];
      acc[h] = x0.x * w0.x + x0.y * w0.y + x0.z * w0.z + x0.w * w0.w +
               x1.x * w1v.x + x1.y * w1v.y + x1.z * w1v.z + x1.w * w1v.w;
    }
#pragma unroll
    for (int off = 32; off > 0; off >>= 1) {
#pragma unroll
      for (int h = 0; h < HH; ++h) acc[h] += __shfl_xor(acc[h], off);
    }
    if (lane == 0) {
      int msk = mask[bs * LL + l];
#pragma unroll
      for (int h = 0; h < HH; ++h) {
        float lg = msk ? acc[h] * INV_TEMP : -1e9f;
        logits[((size_t)bs * HH + h) * LL + l] = lg;
      }
    }
  } else {
    const int n1 = (DI * DD) / 4;
    const int n2 = n1;
    int i = (blk - NLOGIT_BLK) * 256 + threadIdx.x;
    const float4* src;
    unsigned short* dst;
    int j = i;
    if (i < n1)           { src = (const float4*)w1;  dst = w1b; }
    else if (i < n1 + n2) { src = (const float4*)w2;  dst = w2b;  j = i - n1; }
    else                  { src = (const float4*)v_w; dst = v_wb; j = i - n1 - n2; }
    float4 v = src[j];
    dst[j * 4 + 0] = f2b(v.x);
    dst[j * 4 + 1] = f2b(v.y);
    dst[j * 4 + 2] = f2b(v.z);
    dst[j * 4 + 3] = f2b(v.w);
  }
}

__global__ __launch_bounds__(512) void xa_kernel(
    const float* __restrict__ x, const float* __restrict__ logits,
    float* __restrict__ attn_out, unsigned short* __restrict__ xab) {
  int bs = blockIdx.x >> 1, half = blockIdx.x & 1;
  int t = threadIdx.x, wv = t >> 6, lane = t & 63;

  __shared__ float sattn_t[LL][HH];
  __shared__ float sxa[2][HH][256];

  if (wv < 4) {
    for (int h = wv; h < HH; h += 4) {
      const float* lg = logits + ((size_t)bs * HH + h) * LL;
      float v0 = lg[lane], v1 = lg[lane + 64];
      float m = fmaxf(v0, v1);
#pragma unroll
      for (int off = 32; off > 0; off >>= 1) m = fmaxf(m, __shfl_xor(m, off));
      float e0 = __expf(v0 - m), e1 = __expf(v1 - m);
      float s = e0 + e1;
#pragma unroll
      for (int off = 32; off > 0; off >>= 1) s += __shfl_xor(s, off);
      float inv = 1.f / s;
      e0 *= inv; e1 *= inv;
      sattn_t[lane][h]      = e0;
      sattn_t[lane + 64][h] = e1;
      if (half == 0) {
        float* ao = attn_out + ((size_t)bs * HH + h) * LL;
        ao[lane]      = e0;
        ao[lane + 64] = e1;
      }
    }
  }
  __syncthreads();

  int col = t & 255, lseg = t >> 8;
  int e = half * 256 + col;
  const float* xb = x + (size_t)bs * LL * DD;
  float acc[HH];
#pragma unroll
  for (int h = 0; h < HH; ++h) acc[h] = 0.f;
  int l0 = lseg * 64;
  for (int l = l0; l < l0 + 64; ++l) {
    float xv = xb[(size_t)l * DD + e];
    float4 a0 = *(const float4*)&sattn_t[l][0];
    float4 a1 = *(const float4*)&sattn_t[l][4];
    acc[0] += a0.x * xv; acc[1] += a0.y * xv;
    acc[2] += a0.z * xv; acc[3] += a0.w * xv;
    acc[4] += a1.x * xv; acc[5] += a1.y * xv;
    acc[6] += a1.z * xv; acc[7] += a1.w * xv;
  }
#pragma unroll
  for (int h = 0; h < HH; ++h) sxa[lseg][h][col] = acc[h];
  __syncthreads();
  if (t < 256) {
    unsigned short* xo = xab + (size_t)bs * HH * DD;
#pragma unroll
    for (int h = 0; h < HH; ++h)
      xo[h * DD + t + half * 256] = f2b(sxa[0][h][t] + sxa[1][h][t]);
  }
}

__global__ __launch_bounds__(256) void gemm_v_kernel(
    const unsigned short* __restrict__ xab, const unsigned short* __restrict__ v_wb,
    float* __restrict__ vpart) {
  int blk = blockIdx.x;
  int nt = blk & 7, mt = (blk >> 3) & 15, kslice = blk >> 7;
  int wv = threadIdx.x >> 6, lane = threadIdx.x & 63;
  int lm = lane & 15, lq = lane >> 4;

  int m0 = mt * 64 + wv * 16;
  int n0 = nt * 64;
  int g0 = kslice * 16;

  const short8* A0 = (const short8*)(xab + (size_t)(m0 + lm) * DD) + g0;
  const short8* Bp[4];
#pragma unroll
  for (int nf = 0; nf < 4; ++nf)
    Bp[nf] = (const short8*)(v_wb + (size_t)(n0 + nf * 16 + lm) * DD) + g0;

  float4v acc[4];
#pragma unroll
  for (int nf = 0; nf < 4; ++nf) acc[nf] = (float4v){0.f, 0.f, 0.f, 0.f};

#pragma unroll
  for (int ks = 0; ks < 4; ++ks) {
    short8 a0 = A0[ks * 4 + lq];
    short8 b[4];
#pragma unroll
    for (int nf = 0; nf < 4; ++nf) b[nf] = Bp[nf][ks * 4 + lq];
#pragma unroll
    for (int nf = 0; nf < 4; ++nf)
      acc[nf] = __builtin_amdgcn_mfma_f32_16x16x32_bf16(a0, b[nf], acc[nf], 0, 0, 0);
  }

  float* outp = vpart + (size_t)kslice * SLICE;
#pragma unroll
  for (int nf = 0; nf < 4; ++nf) {
    int col = n0 + nf * 16 + lm;
#pragma unroll
    for (int r = 0; r < 4; ++r) {
      int row = m0 + lq * 4 + r;
      outp[(size_t)row * DD + col] = acc[nf][r];
    }
  }
}

__global__ __launch_bounds__(256) void ln_mid_kernel(
    const float* __restrict__ vpart, const float* __restrict__ ln_g,
    const float* __restrict__ ln_b, float* __restrict__ o_ln,
    unsigned short* __restrict__ o_lnb) {
  int wv = threadIdx.x >> 6, lane = threadIdx.x & 63;
  int row = blockIdx.x * 4 + wv;

  const float* p0 = vpart + (size_t)row * DD;
  float vals[8];
  float sum = 0.f, sq = 0.f;
#pragma unroll
  for (int k = 0; k < 8; ++k) {
    int d = lane + 64 * k;
    float v = p0[d] + p0[SLICE + d] + p0[2 * SLICE + d] + p0[3 * SLICE + d];
    vals[k] = v;
    sum += v;
    sq += v * v;
  }
#pragma unroll
  for (int off = 32; off > 0; off >>= 1) {
    sum += __shfl_xor(sum, off);
    sq  += __shfl_xor(sq, off);
  }
  float mu  = sum * (1.f / DD);
  float var = sq * (1.f / DD) - mu * mu;
  float rs  = rsqrtf(var + EPSN);
  float* op = o_ln + (size_t)row * DD;
  unsigned short* opb = o_lnb + (size_t)row * DD;
#pragma unroll
  for (int k = 0; k < 8; ++k) {
    int d = lane + 64 * k;
    float v = (vals[k] - mu) * rs * ln_g[d] + ln_b[d];
    op[d]  = v;
    opb[d] = f2b(v);
  }
}

__global__ __launch_bounds__(256) void gemm1_kernel(
    const unsigned short* __restrict__ xb, const unsigned short* __restrict__ w1b,
    const float* __restrict__ b1, unsigned short* __restrict__ h1b) {
  int blk = blockIdx.x;
  int nt = blk & 31, mt = blk >> 5;
  int wv = threadIdx.x >> 6, lane = threadIdx.x & 63;
  int lm = lane & 15, lq = lane >> 4;

  int m0 = mt * 64 + wv * 16;
  int n0 = nt * 64;

  const short8* A0 = (const short8*)(xb + (size_t)(m0 + lm) * DD);
  const short8* Bp[4];
#pragma unroll
  for (int nf = 0; nf < 4; ++nf)
    Bp[nf] = (const short8*)(w1b + (size_t)(n0 + nf * 16 + lm) * DD);

  float4v acc[4];
#pragma unroll
  for (int nf = 0; nf < 4; ++nf) acc[nf] = (float4v){0.f, 0.f, 0.f, 0.f};

#pragma unroll 4
  for (int ks = 0; ks < DD / 32; ++ks) {
    short8 a0 = A0[ks * 4 + lq];
    short8 b[4];
#pragma unroll
    for (int nf = 0; nf < 4; ++nf) b[nf] = Bp[nf][ks * 4 + lq];
#pragma unroll
    for (int nf = 0; nf < 4; ++nf)
      acc[nf] = __builtin_amdgcn_mfma_f32_16x16x32_bf16(a0, b[nf], acc[nf], 0, 0, 0);
  }

#pragma unroll
  for (int nf = 0; nf < 4; ++nf) {
    int col = n0 + nf * 16 + lm;
    float bb = b1[col];
#pragma unroll
    for (int r = 0; r < 4; ++r) {
      int row = m0 + lq * 4 + r;
      float v = acc[nf][r] + bb;
      h1b[(size_t)row * DI + col] = f2b(fmaxf(v, 0.f));
    }
  }
}

__global__ __launch_bounds__(256) void gemm2_kernel(
    const unsigned short* __restrict__ h1b, const unsigned short* __restrict__ w2b,
    float* __restrict__ ypart) {
  int blk = blockIdx.x;
  int nt = blk & 7, mt = (blk >> 3) & 15, kslice = blk >> 7;
  int wv = threadIdx.x >> 6, lane = threadIdx.x & 63;
  int lm = lane & 15, lq = lane >> 4;

  int m0 = mt * 64 + wv * 16;
  int n0 = nt * 64;
  int g0 = kslice * 64;

  const short8* A0 = (const short8*)(h1b + (size_t)(m0 + lm) * DI) + g0;
  const short8* Bp[4];
#pragma unroll
  for (int nf = 0; nf < 4; ++nf)
    Bp[nf] = (const short8*)(w2b + (size_t)(n0 + nf * 16 + lm) * DI) + g0;

  float4v acc[4];
#pragma unroll
  for (int nf = 0; nf < 4; ++nf) acc[nf] = (float4v){0.f, 0.f, 0.f, 0.f};

#pragma unroll 4
  for (int ks = 0; ks < 16; ++ks) {
    short8 a0 = A0[ks * 4 + lq];
    short8 b[4];
#pragma unroll
    for (int nf = 0; nf < 4; ++nf) b[nf] = Bp[nf][ks * 4 + lq];
#pragma unroll
    for (int nf = 0; nf < 4; ++nf)
      acc[nf] = __builtin_amdgcn_mfma_f32_16x16x32_bf16(a0, b[nf], acc[nf], 0, 0, 0);
  }

  float* outp = ypart + (size_t)kslice * SLICE;
#pragma unroll
  for (int nf = 0; nf < 4; ++nf) {
    int col = n0 + nf * 16 + lm;
#pragma unroll
    for (int r = 0; r < 4; ++r) {
      int row = m0 + lq * 4 + r;
      outp[(size_t)row * DD + col] = acc[nf][r];
    }
  }
}

__global__ __launch_bounds__(256) void ln_final_kernel(
    const float* __restrict__ ypart, const float* __restrict__ o_ln,
    const float* __restrict__ b2, const float* __restrict__ fln_g,
    const float* __restrict__ fln_b, float* __restrict__ y_out) {
  int wv = threadIdx.x >> 6, lane = threadIdx.x & 63;
  int row = blockIdx.x * 4 + wv;

  const float* p0 = ypart + (size_t)row * DD;
  const float* ol = o_ln + (size_t)row * DD;
  float vals[8];
  float sum = 0.f, sq = 0.f;
#pragma unroll
  for (int k = 0; k < 8; ++k) {
    int d = lane + 64 * k;
    float v = p0[d] + p0[SLICE + d] + p0[2 * SLICE + d] + p0[3 * SLICE + d] +
              b2[d] + ol[d];
    vals[k] = v;
    sum += v;
    sq += v * v;
  }
#pragma unroll
  for (int off = 32; off > 0; off >>= 1) {
    sum += __shfl_xor(sum, off);
    sq  += __shfl_xor(sq, off);
  }
  float mu  = sum * (1.f / DD);
  float var = sq * (1.f / DD) - mu * mu;
  float rs  = rsqrtf(var + EPSN);
  float* yo = y_out + (size_t)row * DD;
#pragma unroll
  for (int k = 0; k < 8; ++k) {
    int d = lane + 64 * k;
    yo[d] = (vals[k] - mu) * rs * fln_g[d] + fln_b[d];
  }
}

extern "C" void kernel_launch(void* const* d_in, const int* in_sizes, int n_in,
                              void* d_out, int out_size, void* d_ws, size_t ws_size,
                              hipStream_t stream) {
  MegaParams hp;
  hp.x     = (const float*)d_in[0];
  hp.mask  = (const int*)d_in[1];
  hp.w     = (const float*)d_in[2];
  hp.v_w   = (const float*)d_in[3];
  hp.ln_g  = (const float*)d_in[4];
  hp.ln_b  = (const float*)d_in[5];
  hp.w1    = (const float*)d_in[6];
  hp.b1    = (const float*)d_in[7];
  hp.w2    = (const float*)d_in[8];
  hp.b2    = (const float*)d_in[9];
  hp.fln_g = (const float*)d_in[10];
  hp.fln_b = (const float*)d_in[11];

  hp.y    = (float*)d_out;
  hp.attn = hp.y + (size_t)BB * SS * HH * DD;

  char* ws = (char*)d_ws;
  hp.o_ln   = (float*)(ws);                       // 2 MB
  hp.o_lnb  = (unsigned short*)(ws + 2097152);    // 1 MB
  hp.w1b    = (unsigned short*)(ws + 3145728);    // 2 MB
  hp.w2b    = (unsigned short*)(ws + 5242880);    // 2 MB
  hp.h1b    = (unsigned short*)(ws + 7340032);    // 4 MB
  hp.ypart  = (float*)(ws + 11534336);            // 8 MB (4 slices)
  hp.v_wb   = (unsigned short*)(ws + 19922944);   // 512 KB
  hp.xab    = (unsigned short*)(ws + 20447232);   // 1 MB
  hp.vpart  = (float*)(ws + 21495808);            // 8 MB (4 slices)
  hp.logits = (float*)(ws + 29884416);            // 512 KB

  // Try the cooperative mega-kernel; on ANY failure fall back to the proven
  // 7-kernel pipeline.  Both paths compute identical results, and the chosen
  // path is deterministic for a given device/runtime state.
  hipError_t err = hipErrorUnknown;
  int coop = 0;
  if (hipDeviceGetAttribute(&coop, hipDeviceAttributeCooperativeLaunch, 0) ==
          hipSuccess && coop) {
    void* args[] = { &hp };
    err = hipLaunchCooperativeKernel((const void*)mega_kernel, dim3(GRID),
                                     dim3(BLK), args, 0, stream);
  }
  if (err != hipSuccess) {
    pre_kernel<<<NLOGIT_BLK + NCAST_BLK, 256, 0, stream>>>(
        hp.x, hp.mask, hp.w, hp.w1, hp.w2, hp.v_w, hp.w1b, hp.w2b, hp.v_wb,
        hp.logits);
    xa_kernel<<<BB * SS * 2, 512, 0, stream>>>(hp.x, hp.logits, hp.attn, hp.xab);
    gemm_v_kernel<<<512, 256, 0, stream>>>(hp.xab, hp.v_wb, hp.vpart);
    ln_mid_kernel<<<256, 256, 0, stream>>>(hp.vpart, hp.ln_g, hp.ln_b, hp.o_ln,
                                           hp.o_lnb);
    gemm1_kernel<<<512, 256, 0, stream>>>(hp.o_lnb, hp.w1b, hp.b1, hp.h1b);
    gemm2_kernel<<<512, 256, 0, stream>>>(hp.h1b, hp.w2b, hp.ypart);
    ln_final_kernel<<<256, 256, 0, stream>>>(hp.ypart, hp.o_ln, hp.b2,
                                             hp.fln_g, hp.fln_b, hp.y);
  }
}

// Round 9
// 247.741 us; speedup vs baseline: 1.5255x; 1.5255x over previous
//
#include <hip/hip_runtime.h>
#include <hip/hip_bf16.h>

#define BB 4
#define SS 32
#define HH 8
#define LL 128
#define DD 512
#define DI 2048
#define EPSN 1e-6f
#define INV_TEMP 0.04419417382415922f   // 1/sqrt(512)

#define NLOGIT_BLK 4096                  // B*S*L / 4 waves
#define NCAST_GRAN ((DI*DD/4)*2 + (DD*DD/4))   // 589824 float4 granules
#define NCAST_BLK (NCAST_GRAN / 256)     // 2304

#define SAS 520     // sA row stride (shorts): 1040 B -> rows 4 banks apart
#define H1S 2056    // h1 row stride (shorts): 4112 B -> rows 4 banks apart
#define SYS 516     // sY row stride (floats): 2064 B -> rows 4 banks apart

typedef __attribute__((ext_vector_type(8))) short short8;
typedef __attribute__((ext_vector_type(4))) float float4v;

static __device__ __forceinline__ unsigned short f2b(float f) {
  __hip_bfloat16 h = __float2bfloat16(f);
  return *(unsigned short*)&h;
}
static __device__ __forceinline__ float b2f(unsigned short u) {
  union { unsigned int i; float f; } v;
  v.i = ((unsigned int)u) << 16;
  return v.f;
}

// ---------------------------------------------------------------------------
// K1: fused [logits] + [weight cast].  (proven r5 kernel)
// ---------------------------------------------------------------------------
__global__ __launch_bounds__(256) void pre_kernel(
    const float* __restrict__ x, const int* __restrict__ mask,
    const float* __restrict__ w, const float* __restrict__ w1,
    const float* __restrict__ w2, const float* __restrict__ v_w,
    unsigned short* __restrict__ w1b, unsigned short* __restrict__ w2b,
    unsigned short* __restrict__ v_wb, float* __restrict__ logits) {
  int blk = blockIdx.x;
  if (blk < NLOGIT_BLK) {
    int wv = threadIdx.x >> 6, lane = threadIdx.x & 63;
    int p  = blk * 4 + wv;
    int bs = p >> 7, l = p & (LL - 1);

    const float4* xr = (const float4*)(x + ((size_t)bs * LL + l) * DD) + lane * 2;
    float4 x0 = xr[0], x1 = xr[1];

    float acc[HH];
#pragma unroll
    for (int h = 0; h < HH; ++h) {
      const float4* wr = (const float4*)(w + ((size_t)h * LL + l) * DD) + lane * 2;
      float4 w0 = wr[0], w1v = wr[1];
      acc[h] = x0.x * w0.x + x0.y * w0.y + x0.z * w0.z + x0.w * w0.w +
               x1.x * w1v.x + x1.y * w1v.y + x1.z * w1v.z + x1.w * w1v.w;
    }
#pragma unroll
    for (int off = 32; off > 0; off >>= 1) {
#pragma unroll
      for (int h = 0; h < HH; ++h) acc[h] += __shfl_xor(acc[h], off);
    }
    if (lane == 0) {
      int msk = mask[bs * LL + l];
#pragma unroll
      for (int h = 0; h < HH; ++h) {
        float lg = msk ? acc[h] * INV_TEMP : -1e9f;
        logits[((size_t)bs * HH + h) * LL + l] = lg;
      }
    }
  } else {
    const int n1 = (DI * DD) / 4;
    const int n2 = n1;
    int i = (blk - NLOGIT_BLK) * 256 + threadIdx.x;
    const float4* src;
    unsigned short* dst;
    int j = i;
    if (i < n1)           { src = (const float4*)w1;  dst = w1b; }
    else if (i < n1 + n2) { src = (const float4*)w2;  dst = w2b;  j = i - n1; }
    else                  { src = (const float4*)v_w; dst = v_wb; j = i - n1 - n2; }
    float4 v = src[j];
    dst[j * 4 + 0] = f2b(v.x);
    dst[j * 4 + 1] = f2b(v.y);
    dst[j * 4 + 2] = f2b(v.z);
    dst[j * 4 + 3] = f2b(v.w);
  }
}

// ---------------------------------------------------------------------------
// K2: softmax + xa contraction -> xab bf16.  (proven r5 kernel)
// ---------------------------------------------------------------------------
__global__ __launch_bounds__(512) void xa_kernel(
    const float* __restrict__ x, const float* __restrict__ logits,
    float* __restrict__ attn_out, unsigned short* __restrict__ xab) {
  int bs = blockIdx.x >> 1, half = blockIdx.x & 1;
  int t = threadIdx.x, wv = t >> 6, lane = t & 63;

  __shared__ float sattn_t[LL][HH];
  __shared__ float sxa[2][HH][256];

  if (wv < 4) {
    for (int h = wv; h < HH; h += 4) {
      const float* lg = logits + ((size_t)bs * HH + h) * LL;
      float v0 = lg[lane], v1 = lg[lane + 64];
      float m = fmaxf(v0, v1);
#pragma unroll
      for (int off = 32; off > 0; off >>= 1) m = fmaxf(m, __shfl_xor(m, off));
      float e0 = __expf(v0 - m), e1 = __expf(v1 - m);
      float s = e0 + e1;
#pragma unroll
      for (int off = 32; off > 0; off >>= 1) s += __shfl_xor(s, off);
      float inv = 1.f / s;
      e0 *= inv; e1 *= inv;
      sattn_t[lane][h]      = e0;
      sattn_t[lane + 64][h] = e1;
      if (half == 0) {
        float* ao = attn_out + ((size_t)bs * HH + h) * LL;
        ao[lane]      = e0;
        ao[lane + 64] = e1;
      }
    }
  }
  __syncthreads();

  int col = t & 255, lseg = t >> 8;
  int e = half * 256 + col;
  const float* xb = x + (size_t)bs * LL * DD;
  float acc[HH];
#pragma unroll
  for (int h = 0; h < HH; ++h) acc[h] = 0.f;
  int l0 = lseg * 64;
  for (int l = l0; l < l0 + 64; ++l) {
    float xv = xb[(size_t)l * DD + e];
    float4 a0 = *(const float4*)&sattn_t[l][0];
    float4 a1 = *(const float4*)&sattn_t[l][4];
    acc[0] += a0.x * xv; acc[1] += a0.y * xv;
    acc[2] += a0.z * xv; acc[3] += a0.w * xv;
    acc[4] += a1.x * xv; acc[5] += a1.y * xv;
    acc[6] += a1.z * xv; acc[7] += a1.w * xv;
  }
#pragma unroll
  for (int h = 0; h < HH; ++h) sxa[lseg][h][col] = acc[h];
  __syncthreads();
  if (t < 256) {
    unsigned short* xo = xab + (size_t)bs * HH * DD;
#pragma unroll
    for (int h = 0; h < HH; ++h)
      xo[h * DD + t + half * 256] = f2b(sxa[0][h][t] + sxa[1][h][t]);
  }
}

// ---------------------------------------------------------------------------
// K3: MEGAFFN — the entire post-xa chain for one (b,s) (8 rows), block-local:
//   V:  out = xa @ v_w^T        (MFMA, B=v_w streamed from L2)
//   LN -> xln bf16 (kept in LDS; also the residual source)
//   G1: h1 = relu(xln@w1^T+b1)  (h1 kept in LDS, 8x2048 bf16)
//   G2: y  = h1 @ w2^T
//   final: LN(y + b2 + xln) -> y_out
// 128 blocks x 512 threads (8 waves).  A-fragments use row-duplication
// (lane lm reads LDS row lm&7): D rows 8-15 are discarded duplicates.
// LDS row strides padded so rows land 4 banks apart (conflict-free b128).
// ---------------------------------------------------------------------------
__global__ __launch_bounds__(512, 4) void megaffn_kernel(
    const unsigned short* __restrict__ xab, const unsigned short* __restrict__ v_wb,
    const float* __restrict__ ln_g, const float* __restrict__ ln_b,
    const unsigned short* __restrict__ w1b, const float* __restrict__ b1,
    const unsigned short* __restrict__ w2b, const float* __restrict__ b2,
    const float* __restrict__ fln_g, const float* __restrict__ fln_b,
    float* __restrict__ y_out) {
  int bs = blockIdx.x;
  int t = threadIdx.x, wv = t >> 6, lane = t & 63;
  int lm = lane & 15, lq = lane >> 4;

  __shared__ __attribute__((aligned(16))) unsigned short sA[8 * SAS];  // 8.3 KB
  __shared__ __attribute__((aligned(16))) unsigned short h1[8 * H1S];  // 32.9 KB
  __shared__ __attribute__((aligned(16))) float sY[8 * SYS];           // 16.5 KB

  // load xa strip: 8 rows x 512 bf16 (512 short8 granules, one per thread)
  {
    const short8* src = (const short8*)(xab + (size_t)bs * HH * DD);
    short8 v = src[t];
    *(short8*)&sA[(t >> 6) * SAS + (t & 63) * 8] = v;
  }
  __syncthreads();

  int arow = (lm & 7) * SAS;     // duplicated A rows for lanes 8-15

  // ---- V phase: N=512, wave owns cols wv*64..+63 ----
  {
    int n0 = wv * 64;
#pragma unroll
    for (int nf = 0; nf < 4; ++nf) {
      int n = n0 + nf * 16 + lm;
      const short8* B = (const short8*)(v_wb + (size_t)n * DD);
      float4v acc = (float4v){0.f, 0.f, 0.f, 0.f};
#pragma unroll
      for (int ks = 0; ks < 16; ++ks) {
        short8 a = *(const short8*)&sA[arow + ks * 32 + lq * 8];
        acc = __builtin_amdgcn_mfma_f32_16x16x32_bf16(a, B[ks * 4 + lq], acc, 0, 0, 0);
      }
      if (lq < 2) {
#pragma unroll
        for (int r = 0; r < 4; ++r) sY[(lq * 4 + r) * SYS + n] = acc[r];
      }
    }
  }
  __syncthreads();

  // ---- mid LayerNorm: wave wv handles row wv; write xln bf16 into sA ----
  {
    int row = wv;
    float vals[8];
    float sum = 0.f, sq = 0.f;
#pragma unroll
    for (int k = 0; k < 8; ++k) {
      float v = sY[row * SYS + lane + 64 * k];
      vals[k] = v;
      sum += v;
      sq += v * v;
    }
#pragma unroll
    for (int off = 32; off > 0; off >>= 1) {
      sum += __shfl_xor(sum, off);
      sq  += __shfl_xor(sq, off);
    }
    float mu  = sum * (1.f / DD);
    float var = sq * (1.f / DD) - mu * mu;
    float rs  = rsqrtf(var + EPSN);
#pragma unroll
    for (int k = 0; k < 8; ++k) {
      int d = lane + 64 * k;
      sA[row * SAS + d] = f2b((vals[k] - mu) * rs * ln_g[d] + ln_b[d]);
    }
  }
  __syncthreads();

  // ---- G1: h1 = relu(xln @ w1^T + b1); N=2048, wave owns cols wv*256 ----
  {
    int n0 = wv * 256;
    for (int nf = 0; nf < 16; ++nf) {
      int n = n0 + nf * 16 + lm;
      const short8* B = (const short8*)(w1b + (size_t)n * DD);
      float4v acc = (float4v){0.f, 0.f, 0.f, 0.f};
#pragma unroll
      for (int ks = 0; ks < 16; ++ks) {
        short8 a = *(const short8*)&sA[arow + ks * 32 + lq * 8];
        acc = __builtin_amdgcn_mfma_f32_16x16x32_bf16(a, B[ks * 4 + lq], acc, 0, 0, 0);
      }
      if (lq < 2) {
        float bb = b1[n];
#pragma unroll
        for (int r = 0; r < 4; ++r)
          h1[(lq * 4 + r) * H1S + n] = f2b(fmaxf(acc[r] + bb, 0.f));
      }
    }
  }
  __syncthreads();

  // ---- G2: y = h1 @ w2^T; N=512 K=2048, wave owns cols wv*64 ----
  {
    int hrow = (lm & 7) * H1S;
    int n0 = wv * 64;
#pragma unroll
    for (int nf = 0; nf < 4; ++nf) {
      int n = n0 + nf * 16 + lm;
      const short8* B = (const short8*)(w2b + (size_t)n * DI);
      float4v acc = (float4v){0.f, 0.f, 0.f, 0.f};
#pragma unroll 8
      for (int ks = 0; ks < 64; ++ks) {
        short8 a = *(const short8*)&h1[hrow + ks * 32 + lq * 8];
        acc = __builtin_amdgcn_mfma_f32_16x16x32_bf16(a, B[ks * 4 + lq], acc, 0, 0, 0);
      }
      if (lq < 2) {
#pragma unroll
        for (int r = 0; r < 4; ++r) sY[(lq * 4 + r) * SYS + n] = acc[r];
      }
    }
  }
  __syncthreads();

  // ---- final LN: y = LN(y + b2 + xln)*g + b; wave per row ----
  {
    int row = wv;
    float vals[8];
    float sum = 0.f, sq = 0.f;
#pragma unroll
    for (int k = 0; k < 8; ++k) {
      int d = lane + 64 * k;
      float v = sY[row * SYS + d] + b2[d] + b2f(sA[row * SAS + d]);
      vals[k] = v;
      sum += v;
      sq += v * v;
    }
#pragma unroll
    for (int off = 32; off > 0; off >>= 1) {
      sum += __shfl_xor(sum, off);
      sq  += __shfl_xor(sq, off);
    }
    float mu  = sum * (1.f / DD);
    float var = sq * (1.f / DD) - mu * mu;
    float rs  = rsqrtf(var + EPSN);
    float* yo = y_out + ((size_t)bs * HH + row) * DD;
#pragma unroll
    for (int k = 0; k < 8; ++k) {
      int d = lane + 64 * k;
      yo[d] = (vals[k] - mu) * rs * fln_g[d] + fln_b[d];
    }
  }
}

extern "C" void kernel_launch(void* const* d_in, const int* in_sizes, int n_in,
                              void* d_out, int out_size, void* d_ws, size_t ws_size,
                              hipStream_t stream) {
  const float* x     = (const float*)d_in[0];
  const int*   mask  = (const int*)d_in[1];
  const float* w     = (const float*)d_in[2];
  const float* v_w   = (const float*)d_in[3];
  const float* ln_g  = (const float*)d_in[4];
  const float* ln_b  = (const float*)d_in[5];
  const float* w1    = (const float*)d_in[6];
  const float* b1    = (const float*)d_in[7];
  const float* w2    = (const float*)d_in[8];
  const float* b2    = (const float*)d_in[9];
  const float* fln_g = (const float*)d_in[10];
  const float* fln_b = (const float*)d_in[11];

  float* y    = (float*)d_out;
  float* attn = y + (size_t)BB * SS * HH * DD;

  // workspace layout (bytes)
  char* ws = (char*)d_ws;
  unsigned short* w1b    = (unsigned short*)(ws);               // 2 MB
  unsigned short* w2b    = (unsigned short*)(ws + 2097152);     // 2 MB
  unsigned short* v_wb   = (unsigned short*)(ws + 4194304);     // 512 KB
  unsigned short* xab    = (unsigned short*)(ws + 4718592);     // 1 MB
  float*          logits = (float*)(ws + 5767168);              // 512 KB

  pre_kernel<<<NLOGIT_BLK + NCAST_BLK, 256, 0, stream>>>(
      x, mask, w, w1, w2, v_w, w1b, w2b, v_wb, logits);
  xa_kernel<<<BB * SS * 2, 512, 0, stream>>>(x, logits, attn, xab);
  megaffn_kernel<<<BB * SS, 512, 0, stream>>>(
      xab, v_wb, ln_g, ln_b, w1b, b1, w2b, b2, fln_g, fln_b, y);
}

// Round 10
// 155.103 us; speedup vs baseline: 2.4366x; 1.5973x over previous
//
#include <hip/hip_runtime.h>
#include <hip/hip_bf16.h>

#define BB 4
#define SS 32
#define HH 8
#define LL 128
#define DD 512
#define DI 2048
#define EPSN 1e-6f
#define INV_TEMP 0.04419417382415922f   // 1/sqrt(512)

#define NLOGIT_BLK 4096                  // B*S*L / 4 waves
#define NCAST_GRAN ((DI*DD/4)*2 + (DD*DD/4))   // 589824 float4 granules
#define NCAST_BLK (NCAST_GRAN / 256)     // 2304

#define NROW (BB*SS*HH)                  // 1024 rows
#define SLICE ((size_t)NROW * DD)        // floats per K-split partial

typedef __attribute__((ext_vector_type(8))) short short8;
typedef __attribute__((ext_vector_type(4))) float float4v;

static __device__ __forceinline__ unsigned short f2b(float f) {
  __hip_bfloat16 h = __float2bfloat16(f);
  return *(unsigned short*)&h;
}

// Fragment-packed layout: element (m,k) of an (M x K) operand lives at
//   panel p=m>>4, chunk c=k>>5, quad lq=(k>>3)&3, lane lm=m&15, elem e=k&7
//   index = ((p*(K/32)+c)*64 + lq*16 + lm)*8 + e
// so a wave's MFMA fragment (16x16x32 bf16, A or B role) is ONE contiguous
// 1 KB read: granule g = (p*(K/32)+c)*64 + lane.
static __device__ __forceinline__ size_t pk(int m, int k, int K) {
  return ((((size_t)(m >> 4) * (K >> 5) + (k >> 5)) * 4 + ((k >> 3) & 3)) * 16
          + (m & 15)) * 8 + (k & 7);
}

// ---------------------------------------------------------------------------
// K1: fused [logits] + [weight cast -> fragment-packed bf16].
// ---------------------------------------------------------------------------
__global__ __launch_bounds__(256) void pre_kernel(
    const float* __restrict__ x, const int* __restrict__ mask,
    const float* __restrict__ w, const float* __restrict__ w1,
    const float* __restrict__ w2, const float* __restrict__ v_w,
    unsigned short* __restrict__ w1b, unsigned short* __restrict__ w2b,
    unsigned short* __restrict__ v_wb, float* __restrict__ logits) {
  int blk = blockIdx.x;
  if (blk < NLOGIT_BLK) {
    int wv = threadIdx.x >> 6, lane = threadIdx.x & 63;
    int p  = blk * 4 + wv;
    int bs = p >> 7, l = p & (LL - 1);

    const float4* xr = (const float4*)(x + ((size_t)bs * LL + l) * DD) + lane * 2;
    float4 x0 = xr[0], x1 = xr[1];

    float acc[HH];
#pragma unroll
    for (int h = 0; h < HH; ++h) {
      const float4* wr = (const float4*)(w + ((size_t)h * LL + l) * DD) + lane * 2;
      float4 w0 = wr[0], w1v = wr[1];
      acc[h] = x0.x * w0.x + x0.y * w0.y + x0.z * w0.z + x0.w * w0.w +
               x1.x * w1v.x + x1.y * w1v.y + x1.z * w1v.z + x1.w * w1v.w;
    }
#pragma unroll
    for (int off = 32; off > 0; off >>= 1) {
#pragma unroll
      for (int h = 0; h < HH; ++h) acc[h] += __shfl_xor(acc[h], off);
    }
    if (lane == 0) {
      int msk = mask[bs * LL + l];
#pragma unroll
      for (int h = 0; h < HH; ++h) {
        float lg = msk ? acc[h] * INV_TEMP : -1e9f;
        logits[((size_t)bs * HH + h) * LL + l] = lg;
      }
    }
  } else {
    const int n1 = (DI * DD) / 4;    // w1 granules (N=2048,K=512)
    const int n2 = n1;               // w2 granules (N=512, K=2048)
    int i = (blk - NLOGIT_BLK) * 256 + threadIdx.x;
    float4 v;
    unsigned short* dst;
    size_t base;
    if (i < n1) {
      v = ((const float4*)w1)[i];
      dst = w1b;
      base = pk(i >> 7, (i & 127) * 4, DD);
    } else if (i < n1 + n2) {
      int j = i - n1;
      v = ((const float4*)w2)[j];
      dst = w2b;
      base = pk(j >> 9, (j & 511) * 4, DI);
    } else {
      int j = i - n1 - n2;
      v = ((const float4*)v_w)[j];
      dst = v_wb;
      base = pk(j >> 7, (j & 127) * 4, DD);
    }
    dst[base + 0] = f2b(v.x);
    dst[base + 1] = f2b(v.y);
    dst[base + 2] = f2b(v.z);
    dst[base + 3] = f2b(v.w);
  }
}

// ---------------------------------------------------------------------------
// K2: softmax + xa contraction -> xab (fragment-packed bf16, M=1024 K=512).
// ---------------------------------------------------------------------------
__global__ __launch_bounds__(512) void xa_kernel(
    const float* __restrict__ x, const float* __restrict__ logits,
    float* __restrict__ attn_out, unsigned short* __restrict__ xab) {
  int bs = blockIdx.x >> 1, half = blockIdx.x & 1;
  int t = threadIdx.x, wv = t >> 6, lane = t & 63;

  __shared__ float sattn_t[LL][HH];
  __shared__ float sxa[2][HH][256];

  if (wv < 4) {
    for (int h = wv; h < HH; h += 4) {
      const float* lg = logits + ((size_t)bs * HH + h) * LL;
      float v0 = lg[lane], v1 = lg[lane + 64];
      float m = fmaxf(v0, v1);
#pragma unroll
      for (int off = 32; off > 0; off >>= 1) m = fmaxf(m, __shfl_xor(m, off));
      float e0 = __expf(v0 - m), e1 = __expf(v1 - m);
      float s = e0 + e1;
#pragma unroll
      for (int off = 32; off > 0; off >>= 1) s += __shfl_xor(s, off);
      float inv = 1.f / s;
      e0 *= inv; e1 *= inv;
      sattn_t[lane][h]      = e0;
      sattn_t[lane + 64][h] = e1;
      if (half == 0) {
        float* ao = attn_out + ((size_t)bs * HH + h) * LL;
        ao[lane]      = e0;
        ao[lane + 64] = e1;
      }
    }
  }
  __syncthreads();

  int col = t & 255, lseg = t >> 8;
  int e = half * 256 + col;
  const float* xb = x + (size_t)bs * LL * DD;
  float acc[HH];
#pragma unroll
  for (int h = 0; h < HH; ++h) acc[h] = 0.f;
  int l0 = lseg * 64;
  for (int l = l0; l < l0 + 64; ++l) {
    float xv = xb[(size_t)l * DD + e];
    float4 a0 = *(const float4*)&sattn_t[l][0];
    float4 a1 = *(const float4*)&sattn_t[l][4];
    acc[0] += a0.x * xv; acc[1] += a0.y * xv;
    acc[2] += a0.z * xv; acc[3] += a0.w * xv;
    acc[4] += a1.x * xv; acc[5] += a1.y * xv;
    acc[6] += a1.z * xv; acc[7] += a1.w * xv;
  }
#pragma unroll
  for (int h = 0; h < HH; ++h) sxa[lseg][h][col] = acc[h];
  __syncthreads();
  if (t < 256) {
#pragma unroll
    for (int h = 0; h < HH; ++h) {
      int m = bs * HH + h;
      xab[pk(m, e, DD)] = f2b(sxa[0][h][t] + sxa[1][h][t]);
    }
  }
}

// ---------------------------------------------------------------------------
// K3: GEMM_V  vpart[ks] = xa @ v_w^T.  M=1024 N=512 K=512, K-split x4.
// Block 64x64, 4 waves.  All fragment loads coalesced (packed operands).
// ---------------------------------------------------------------------------
__global__ __launch_bounds__(256) void gemm_v_kernel(
    const unsigned short* __restrict__ xab, const unsigned short* __restrict__ v_wb,
    float* __restrict__ vpart) {
  int blk = blockIdx.x;
  int nt = blk & 7, mt = (blk >> 3) & 15, kslice = blk >> 7;
  int wv = threadIdx.x >> 6, lane = threadIdx.x & 63;
  int lm = lane & 15, lq = lane >> 4;

  int m0 = mt * 64 + wv * 16;
  int n0 = nt * 64;
  const short8* A8 = (const short8*)xab + (size_t)(m0 >> 4) * 16 * 64;
  const short8* B8 = (const short8*)v_wb;

  float4v acc[4];
#pragma unroll
  for (int nf = 0; nf < 4; ++nf) acc[nf] = (float4v){0.f, 0.f, 0.f, 0.f};

#pragma unroll
  for (int ci = 0; ci < 4; ++ci) {
    int c = kslice * 4 + ci;
    short8 a = A8[(size_t)c * 64 + lane];
#pragma unroll
    for (int nf = 0; nf < 4; ++nf) {
      short8 b = B8[((size_t)((n0 >> 4) + nf) * 16 + c) * 64 + lane];
      acc[nf] = __builtin_amdgcn_mfma_f32_16x16x32_bf16(a, b, acc[nf], 0, 0, 0);
    }
  }

  float* outp = vpart + (size_t)kslice * SLICE;
#pragma unroll
  for (int nf = 0; nf < 4; ++nf) {
    int col = n0 + nf * 16 + lm;
#pragma unroll
    for (int r = 0; r < 4; ++r)
      outp[(size_t)(m0 + lq * 4 + r) * DD + col] = acc[nf][r];
  }
}

// ---------------------------------------------------------------------------
// K4: mid LayerNorm over 4 partials -> o_ln fp32 + o_lnb (packed bf16).
// ---------------------------------------------------------------------------
__global__ __launch_bounds__(256) void ln_mid_kernel(
    const float* __restrict__ vpart, const float* __restrict__ ln_g,
    const float* __restrict__ ln_b, float* __restrict__ o_ln,
    unsigned short* __restrict__ o_lnb) {
  int wv = threadIdx.x >> 6, lane = threadIdx.x & 63;
  int row = blockIdx.x * 4 + wv;

  const float* p0 = vpart + (size_t)row * DD;
  float vals[8];
  float sum = 0.f, sq = 0.f;
#pragma unroll
  for (int k = 0; k < 8; ++k) {
    int d = lane + 64 * k;
    float v = p0[d] + p0[SLICE + d] + p0[2 * SLICE + d] + p0[3 * SLICE + d];
    vals[k] = v;
    sum += v;
    sq += v * v;
  }
#pragma unroll
  for (int off = 32; off > 0; off >>= 1) {
    sum += __shfl_xor(sum, off);
    sq  += __shfl_xor(sq, off);
  }
  float mu  = sum * (1.f / DD);
  float var = sq * (1.f / DD) - mu * mu;
  float rs  = rsqrtf(var + EPSN);
  float* op = o_ln + (size_t)row * DD;
#pragma unroll
  for (int k = 0; k < 8; ++k) {
    int d = lane + 64 * k;
    float v = (vals[k] - mu) * rs * ln_g[d] + ln_b[d];
    op[d] = v;
    o_lnb[pk(row, d, DD)] = f2b(v);
  }
}

// ---------------------------------------------------------------------------
// K5: GEMM1  h1 = relu(xln @ w1^T + b1) -> h1b (packed, A-role K=2048).
// M=1024 N=2048 K=512.  Block 64x64, 4 waves.  grid=512.
// ---------------------------------------------------------------------------
__global__ __launch_bounds__(256) void gemm1_kernel(
    const unsigned short* __restrict__ o_lnb, const unsigned short* __restrict__ w1b,
    const float* __restrict__ b1, unsigned short* __restrict__ h1b) {
  int blk = blockIdx.x;
  int nt = blk & 31, mt = blk >> 5;
  int wv = threadIdx.x >> 6, lane = threadIdx.x & 63;
  int lm = lane & 15, lq = lane >> 4;

  int m0 = mt * 64 + wv * 16;
  int n0 = nt * 64;
  const short8* A8 = (const short8*)o_lnb + (size_t)(m0 >> 4) * 16 * 64;
  const short8* B8 = (const short8*)w1b;

  float4v acc[4];
#pragma unroll
  for (int nf = 0; nf < 4; ++nf) acc[nf] = (float4v){0.f, 0.f, 0.f, 0.f};

#pragma unroll 4
  for (int c = 0; c < 16; ++c) {
    short8 a = A8[(size_t)c * 64 + lane];
#pragma unroll
    for (int nf = 0; nf < 4; ++nf) {
      short8 b = B8[((size_t)((n0 >> 4) + nf) * 16 + c) * 64 + lane];
      acc[nf] = __builtin_amdgcn_mfma_f32_16x16x32_bf16(a, b, acc[nf], 0, 0, 0);
    }
  }

#pragma unroll
  for (int nf = 0; nf < 4; ++nf) {
    int col = n0 + nf * 16 + lm;
    float bb = b1[col];
#pragma unroll
    for (int r = 0; r < 4; ++r) {
      int row = m0 + lq * 4 + r;
      h1b[pk(row, col, DI)] = f2b(fmaxf(acc[nf][r] + bb, 0.f));
    }
  }
}

// ---------------------------------------------------------------------------
// K6: GEMM2  ypart[ks] = h1 @ w2^T.  M=1024 N=512 K=2048, K-split x4.
// Block 64x64, 4 waves.  grid=512.
// ---------------------------------------------------------------------------
__global__ __launch_bounds__(256) void gemm2_kernel(
    const unsigned short* __restrict__ h1b, const unsigned short* __restrict__ w2b,
    float* __restrict__ ypart) {
  int blk = blockIdx.x;
  int nt = blk & 7, mt = (blk >> 3) & 15, kslice = blk >> 7;
  int wv = threadIdx.x >> 6, lane = threadIdx.x & 63;
  int lm = lane & 15, lq = lane >> 4;

  int m0 = mt * 64 + wv * 16;
  int n0 = nt * 64;
  const short8* A8 = (const short8*)h1b + (size_t)(m0 >> 4) * 64 * 64;   // K/32=64
  const short8* B8 = (const short8*)w2b;

  float4v acc[4];
#pragma unroll
  for (int nf = 0; nf < 4; ++nf) acc[nf] = (float4v){0.f, 0.f, 0.f, 0.f};

#pragma unroll 4
  for (int ci = 0; ci < 16; ++ci) {
    int c = kslice * 16 + ci;
    short8 a = A8[(size_t)c * 64 + lane];
#pragma unroll
    for (int nf = 0; nf < 4; ++nf) {
      short8 b = B8[((size_t)((n0 >> 4) + nf) * 64 + c) * 64 + lane];
      acc[nf] = __builtin_amdgcn_mfma_f32_16x16x32_bf16(a, b, acc[nf], 0, 0, 0);
    }
  }

  float* outp = ypart + (size_t)kslice * SLICE;
#pragma unroll
  for (int nf = 0; nf < 4; ++nf) {
    int col = n0 + nf * 16 + lm;
#pragma unroll
    for (int r = 0; r < 4; ++r)
      outp[(size_t)(m0 + lq * 4 + r) * DD + col] = acc[nf][r];
  }
}

// ---------------------------------------------------------------------------
// K7: final LN:  y = LN(sum ypart + b2 + o_ln)*g + b.
// ---------------------------------------------------------------------------
__global__ __launch_bounds__(256) void ln_final_kernel(
    const float* __restrict__ ypart, const float* __restrict__ o_ln,
    const float* __restrict__ b2, const float* __restrict__ fln_g,
    const float* __restrict__ fln_b, float* __restrict__ y_out) {
  int wv = threadIdx.x >> 6, lane = threadIdx.x & 63;
  int row = blockIdx.x * 4 + wv;

  const float* p0 = ypart + (size_t)row * DD;
  const float* ol = o_ln + (size_t)row * DD;
  float vals[8];
  float sum = 0.f, sq = 0.f;
#pragma unroll
  for (int k = 0; k < 8; ++k) {
    int d = lane + 64 * k;
    float v = p0[d] + p0[SLICE + d] + p0[2 * SLICE + d] + p0[3 * SLICE + d] +
              b2[d] + ol[d];
    vals[k] = v;
    sum += v;
    sq += v * v;
  }
#pragma unroll
  for (int off = 32; off > 0; off >>= 1) {
    sum += __shfl_xor(sum, off);
    sq  += __shfl_xor(sq, off);
  }
  float mu  = sum * (1.f / DD);
  float var = sq * (1.f / DD) - mu * mu;
  float rs  = rsqrtf(var + EPSN);
  float* yo = y_out + (size_t)row * DD;
#pragma unroll
  for (int k = 0; k < 8; ++k) {
    int d = lane + 64 * k;
    yo[d] = (vals[k] - mu) * rs * fln_g[d] + fln_b[d];
  }
}

extern "C" void kernel_launch(void* const* d_in, const int* in_sizes, int n_in,
                              void* d_out, int out_size, void* d_ws, size_t ws_size,
                              hipStream_t stream) {
  const float* x     = (const float*)d_in[0];
  const int*   mask  = (const int*)d_in[1];
  const float* w     = (const float*)d_in[2];
  const float* v_w   = (const float*)d_in[3];
  const float* ln_g  = (const float*)d_in[4];
  const float* ln_b  = (const float*)d_in[5];
  const float* w1    = (const float*)d_in[6];
  const float* b1    = (const float*)d_in[7];
  const float* w2    = (const float*)d_in[8];
  const float* b2    = (const float*)d_in[9];
  const float* fln_g = (const float*)d_in[10];
  const float* fln_b = (const float*)d_in[11];

  float* y    = (float*)d_out;
  float* attn = y + (size_t)BB * SS * HH * DD;

  // workspace layout (bytes)
  char* ws = (char*)d_ws;
  float*          o_ln   = (float*)(ws);                       // 2 MB
  unsigned short* o_lnb  = (unsigned short*)(ws + 2097152);    // 1 MB
  unsigned short* w1b    = (unsigned short*)(ws + 3145728);    // 2 MB
  unsigned short* w2b    = (unsigned short*)(ws + 5242880);    // 2 MB
  unsigned short* h1b    = (unsigned short*)(ws + 7340032);    // 4 MB
  float*          ypart  = (float*)(ws + 11534336);            // 8 MB (4 slices)
  unsigned short* v_wb   = (unsigned short*)(ws + 19922944);   // 512 KB
  unsigned short* xab    = (unsigned short*)(ws + 20447232);   // 1 MB
  float*          vpart  = (float*)(ws + 21495808);            // 8 MB (4 slices)
  float*          logits = (float*)(ws + 29884416);            // 512 KB

  pre_kernel<<<NLOGIT_BLK + NCAST_BLK, 256, 0, stream>>>(
      x, mask, w, w1, w2, v_w, w1b, w2b, v_wb, logits);
  xa_kernel<<<BB * SS * 2, 512, 0, stream>>>(x, logits, attn, xab);
  gemm_v_kernel<<<512, 256, 0, stream>>>(xab, v_wb, vpart);
  ln_mid_kernel<<<256, 256, 0, stream>>>(vpart, ln_g, ln_b, o_ln, o_lnb);
  gemm1_kernel<<<512, 256, 0, stream>>>(o_lnb, w1b, b1, h1b);
  gemm2_kernel<<<512, 256, 0, stream>>>(h1b, w2b, ypart);
  ln_final_kernel<<<256, 256, 0, stream>>>(ypart, o_ln, b2, fln_g, fln_b, y);
}